// Round 2
// baseline (7002.014 us; speedup 1.0000x reference)
//
#include <hip/hip_runtime.h>

#define T_SEQ 2048
#define NB 4
#define NH 16
#define HD 64
#define CDIM 1024
#define MROWS (NB * T_SEQ)  // 8192

// ---------------- GEMM: C[m,n] = sum_k A[m,k] * B[n,k]  (fp32, B given [N,K])
// mode 0: plain write to O0 [M,N]
// mode 1: QKV scatter into O0/O1/O2 as [B,H,T,D]
#define BM 64
#define BN 64
#define BK 32

__global__ __launch_bounds__(256) void gemm_bt(
    const float* __restrict__ A,
    const float* __restrict__ Bm,
    float* __restrict__ O0,
    float* __restrict__ O1,
    float* __restrict__ O2,
    const int N, const int K, const int mode)
{
  __shared__ float As[BK][BM + 4];  // transposed: As[k][m]
  __shared__ float Bs[BK][BN + 4];
  const int tid = threadIdx.x;
  const int tx = tid & 15;        // n-direction
  const int ty = tid >> 4;        // m-direction
  const int m0 = blockIdx.y * BM;
  const int n0 = blockIdx.x * BN;
  const int lr = tid >> 3;        // 0..31: tile row (two passes: lr, lr+32)
  const int lc = (tid & 7) << 2;  // 0,4,...,28: k-col group (float4)

  float acc[4][4] = {{0.f, 0.f, 0.f, 0.f}, {0.f, 0.f, 0.f, 0.f},
                     {0.f, 0.f, 0.f, 0.f}, {0.f, 0.f, 0.f, 0.f}};

  const float* Ap0 = A  + (size_t)(m0 + lr) * K + lc;
  const float* Ap1 = A  + (size_t)(m0 + lr + 32) * K + lc;
  const float* Bp0 = Bm + (size_t)(n0 + lr) * K + lc;
  const float* Bp1 = Bm + (size_t)(n0 + lr + 32) * K + lc;

  for (int k0 = 0; k0 < K; k0 += BK) {
    const float4 a0 = *(const float4*)(Ap0 + k0);
    const float4 a1 = *(const float4*)(Ap1 + k0);
    const float4 b0 = *(const float4*)(Bp0 + k0);
    const float4 b1 = *(const float4*)(Bp1 + k0);
    As[lc + 0][lr] = a0.x; As[lc + 1][lr] = a0.y; As[lc + 2][lr] = a0.z; As[lc + 3][lr] = a0.w;
    As[lc + 0][lr + 32] = a1.x; As[lc + 1][lr + 32] = a1.y; As[lc + 2][lr + 32] = a1.z; As[lc + 3][lr + 32] = a1.w;
    Bs[lc + 0][lr] = b0.x; Bs[lc + 1][lr] = b0.y; Bs[lc + 2][lr] = b0.z; Bs[lc + 3][lr] = b0.w;
    Bs[lc + 0][lr + 32] = b1.x; Bs[lc + 1][lr + 32] = b1.y; Bs[lc + 2][lr + 32] = b1.z; Bs[lc + 3][lr + 32] = b1.w;
    __syncthreads();
#pragma unroll
    for (int kk = 0; kk < BK; ++kk) {
      const float4 a4 = *(const float4*)&As[kk][ty << 2];
      const float4 b4 = *(const float4*)&Bs[kk][tx << 2];
      const float ar[4] = {a4.x, a4.y, a4.z, a4.w};
      const float br[4] = {b4.x, b4.y, b4.z, b4.w};
#pragma unroll
      for (int i = 0; i < 4; ++i)
#pragma unroll
        for (int j = 0; j < 4; ++j)
          acc[i][j] += ar[i] * br[j];
    }
    __syncthreads();
  }

  if (mode == 0) {
#pragma unroll
    for (int i = 0; i < 4; ++i) {
      const int m = m0 + (ty << 2) + i;
      float4 pk = make_float4(acc[i][0], acc[i][1], acc[i][2], acc[i][3]);
      *(float4*)(O0 + (size_t)m * N + n0 + (tx << 2)) = pk;
    }
  } else {
    // n-tile (64 wide, 64-aligned) lies entirely inside one head of one of q/k/v
    const int which = n0 >> 10;              // 0=q 1=k 2=v
    const int h = (n0 >> 6) & (NH - 1);
    float* dst = (which == 0) ? O0 : (which == 1) ? O1 : O2;
#pragma unroll
    for (int i = 0; i < 4; ++i) {
      const int m = m0 + (ty << 2) + i;
      const int b = m >> 11;                 // m / T_SEQ
      const int t = m & (T_SEQ - 1);
      float4 pk = make_float4(acc[i][0], acc[i][1], acc[i][2], acc[i][3]);
      *(float4*)(dst + (((size_t)(b * NH + h) * T_SEQ + t) << 6) + (tx << 2)) = pk;
    }
  }
}

// ---------------- Causal attention: one block (128 thr) per (b,h,query)
// Q,K,V: [B,H,T,D] fp32.  O: [B,T,C] fp32 (so proj GEMM reads contiguous rows)
__global__ __launch_bounds__(128) void attn_kernel(
    const float* __restrict__ Q,
    const float* __restrict__ Kb,
    const float* __restrict__ Vb,
    float* __restrict__ O)
{
  const int qi = blockIdx.x;        // query index 0..T-1
  const int bh = blockIdx.y;        // b*NH + h
  const int b = bh >> 4, h = bh & 15;
  __shared__ float qs[HD];
  __shared__ float sc[T_SEQ];
  __shared__ float red[4];
  __shared__ float part[128];
  const int tid = threadIdx.x;
  const size_t headoff = (size_t)bh * T_SEQ * HD;
  const float* Kh = Kb + headoff;
  const float* Vh = Vb + headoff;

  if (tid < HD) qs[tid] = Q[headoff + ((size_t)qi << 6) + tid] * 0.125f; // 1/sqrt(64)
  __syncthreads();

  const int nk = qi + 1;            // causal: keys 0..qi inclusive
  float lmax = -1e30f;
  for (int j = tid; j < nk; j += 128) {
    const float* kr = Kh + ((size_t)j << 6);
    float dot = 0.f;
#pragma unroll
    for (int c = 0; c < 16; ++c) {
      const float4 u = *(const float4*)(kr + (c << 2));
      dot += qs[(c << 2) + 0] * u.x + qs[(c << 2) + 1] * u.y
           + qs[(c << 2) + 2] * u.z + qs[(c << 2) + 3] * u.w;
    }
    sc[j] = dot;
    lmax = fmaxf(lmax, dot);
  }
#pragma unroll
  for (int off = 32; off; off >>= 1) lmax = fmaxf(lmax, __shfl_down(lmax, off));
  if ((tid & 63) == 0) red[tid >> 6] = lmax;
  __syncthreads();
  const float mx = fmaxf(red[0], red[1]);

  float lsum = 0.f;
  for (int j = tid; j < nk; j += 128) {
    const float w = __expf(sc[j] - mx);
    sc[j] = w;
    lsum += w;
  }
#pragma unroll
  for (int off = 32; off; off >>= 1) lsum += __shfl_down(lsum, off);
  if ((tid & 63) == 0) red[2 + (tid >> 6)] = lsum;
  __syncthreads();
  const float inv = 1.f / (red[2] + red[3]);

  // PV: 2 sub-waves, each wave reads coalesced V rows (64 lanes = 256B/row)
  const int d = tid & 63;
  const int s = tid >> 6;
  float acc = 0.f;
  for (int j = s; j < nk; j += 2)
    acc += sc[j] * Vh[((size_t)j << 6) + d];
  part[tid] = acc;
  __syncthreads();
  if (s == 0) {
    const float o = (part[d] + part[64 + d]) * inv;
    O[(size_t)(b * T_SEQ + qi) * CDIM + (h << 6) + d] = o;
  }
}

extern "C" void kernel_launch(void* const* d_in, const int* in_sizes, int n_in,
                              void* d_out, int out_size, void* d_ws, size_t ws_size,
                              hipStream_t stream) {
  const float* x     = (const float*)d_in[0];  // [B,T,C]
  const float* Wqkv  = (const float*)d_in[1];  // [3C,C]
  const float* Wproj = (const float*)d_in[2];  // [C,C]
  float* out = (float*)d_out;                  // [B,T,C]

  const size_t HSZ = (size_t)NB * NH * T_SEQ * HD;  // 8388608 elems
  float* qbuf = (float*)d_ws;
  float* kbuf = qbuf + HSZ;
  float* vbuf = kbuf + HSZ;
  float* abuf = vbuf + HSZ;                    // [B,T,C] attention output

  // 1) QKV projection, scattered to [B,H,T,D]
  dim3 g1(3 * CDIM / BN, MROWS / BM);   // (48,128)
  gemm_bt<<<g1, 256, 0, stream>>>(x, Wqkv, qbuf, kbuf, vbuf, 3 * CDIM, CDIM, 1);

  // 2) causal softmax attention
  dim3 g2(T_SEQ, NB * NH);              // (2048,64)
  attn_kernel<<<g2, 128, 0, stream>>>(qbuf, kbuf, vbuf, abuf);

  // 3) output projection
  dim3 g3(CDIM / BN, MROWS / BM);       // (16,128)
  gemm_bt<<<g3, 256, 0, stream>>>(abuf, Wproj, out, nullptr, nullptr, CDIM, CDIM, 0);
}

// Round 3
// 1275.119 us; speedup vs baseline: 5.4913x; 5.4913x over previous
//
#include <hip/hip_runtime.h>

#define T_SEQ 2048
#define NB 4
#define NH 16
#define HD 64
#define CDIM 1024
#define MROWS (NB * T_SEQ)  // 8192

typedef __attribute__((ext_vector_type(8))) short short8;
typedef __attribute__((ext_vector_type(4))) float floatx4;

static __device__ __forceinline__ unsigned short f2bf(float f) {
  union { float f; unsigned int i; } c; c.f = f;
  return (unsigned short)((c.i + 0x7FFFu + ((c.i >> 16) & 1u)) >> 16);
}

// ================= fp32 tiled GEMM  C[m,n] = sum_k A[m,k]*B[n,k] =================
#define BM 64
#define BN 64
#define BK 32

// QKV variant: epilogue scatters bf16 into q/k/v [B,H,T,D]
__global__ __launch_bounds__(256) void gemm_qkv(
    const float* __restrict__ A, const float* __restrict__ Bm,
    unsigned short* __restrict__ Oq, unsigned short* __restrict__ Ok,
    unsigned short* __restrict__ Ov, const int N, const int K)
{
  __shared__ float As[BK][BM + 4];
  __shared__ float Bs[BK][BN + 4];
  const int tid = threadIdx.x;
  const int tx = tid & 15, ty = tid >> 4;
  const int m0 = blockIdx.y * BM, n0 = blockIdx.x * BN;
  const int lr = tid >> 3, lc = (tid & 7) << 2;

  float acc[4][4] = {{0.f,0.f,0.f,0.f},{0.f,0.f,0.f,0.f},{0.f,0.f,0.f,0.f},{0.f,0.f,0.f,0.f}};
  const float* Ap0 = A  + (size_t)(m0 + lr) * K + lc;
  const float* Ap1 = A  + (size_t)(m0 + lr + 32) * K + lc;
  const float* Bp0 = Bm + (size_t)(n0 + lr) * K + lc;
  const float* Bp1 = Bm + (size_t)(n0 + lr + 32) * K + lc;

  for (int k0 = 0; k0 < K; k0 += BK) {
    const float4 a0 = *(const float4*)(Ap0 + k0);
    const float4 a1 = *(const float4*)(Ap1 + k0);
    const float4 b0 = *(const float4*)(Bp0 + k0);
    const float4 b1 = *(const float4*)(Bp1 + k0);
    As[lc+0][lr] = a0.x; As[lc+1][lr] = a0.y; As[lc+2][lr] = a0.z; As[lc+3][lr] = a0.w;
    As[lc+0][lr+32] = a1.x; As[lc+1][lr+32] = a1.y; As[lc+2][lr+32] = a1.z; As[lc+3][lr+32] = a1.w;
    Bs[lc+0][lr] = b0.x; Bs[lc+1][lr] = b0.y; Bs[lc+2][lr] = b0.z; Bs[lc+3][lr] = b0.w;
    Bs[lc+0][lr+32] = b1.x; Bs[lc+1][lr+32] = b1.y; Bs[lc+2][lr+32] = b1.z; Bs[lc+3][lr+32] = b1.w;
    __syncthreads();
#pragma unroll
    for (int kk = 0; kk < BK; ++kk) {
      const float4 a4 = *(const float4*)&As[kk][ty << 2];
      const float4 b4 = *(const float4*)&Bs[kk][tx << 2];
      const float ar[4] = {a4.x, a4.y, a4.z, a4.w};
      const float br[4] = {b4.x, b4.y, b4.z, b4.w};
#pragma unroll
      for (int i = 0; i < 4; ++i)
#pragma unroll
        for (int j = 0; j < 4; ++j) acc[i][j] += ar[i] * br[j];
    }
    __syncthreads();
  }
  // n-tile (64 wide) lies inside one head of one of q/k/v
  const int which = n0 >> 10;
  const int h = (n0 >> 6) & (NH - 1);
  unsigned short* dst = (which == 0) ? Oq : (which == 1) ? Ok : Ov;
#pragma unroll
  for (int i = 0; i < 4; ++i) {
    const int m = m0 + (ty << 2) + i;
    const int b = m >> 11, t = m & (T_SEQ - 1);
    ushort4 pk;
    pk.x = f2bf(acc[i][0]); pk.y = f2bf(acc[i][1]);
    pk.z = f2bf(acc[i][2]); pk.w = f2bf(acc[i][3]);
    *(ushort4*)(dst + (((size_t)(b * NH + h) * T_SEQ + t) << 6) + (tx << 2)) = pk;
  }
}

// Proj variant: plain fp32 [M,N] output
__global__ __launch_bounds__(256) void gemm_proj(
    const float* __restrict__ A, const float* __restrict__ Bm,
    float* __restrict__ O0, const int N, const int K)
{
  __shared__ float As[BK][BM + 4];
  __shared__ float Bs[BK][BN + 4];
  const int tid = threadIdx.x;
  const int tx = tid & 15, ty = tid >> 4;
  const int m0 = blockIdx.y * BM, n0 = blockIdx.x * BN;
  const int lr = tid >> 3, lc = (tid & 7) << 2;

  float acc[4][4] = {{0.f,0.f,0.f,0.f},{0.f,0.f,0.f,0.f},{0.f,0.f,0.f,0.f},{0.f,0.f,0.f,0.f}};
  const float* Ap0 = A  + (size_t)(m0 + lr) * K + lc;
  const float* Ap1 = A  + (size_t)(m0 + lr + 32) * K + lc;
  const float* Bp0 = Bm + (size_t)(n0 + lr) * K + lc;
  const float* Bp1 = Bm + (size_t)(n0 + lr + 32) * K + lc;

  for (int k0 = 0; k0 < K; k0 += BK) {
    const float4 a0 = *(const float4*)(Ap0 + k0);
    const float4 a1 = *(const float4*)(Ap1 + k0);
    const float4 b0 = *(const float4*)(Bp0 + k0);
    const float4 b1 = *(const float4*)(Bp1 + k0);
    As[lc+0][lr] = a0.x; As[lc+1][lr] = a0.y; As[lc+2][lr] = a0.z; As[lc+3][lr] = a0.w;
    As[lc+0][lr+32] = a1.x; As[lc+1][lr+32] = a1.y; As[lc+2][lr+32] = a1.z; As[lc+3][lr+32] = a1.w;
    Bs[lc+0][lr] = b0.x; Bs[lc+1][lr] = b0.y; Bs[lc+2][lr] = b0.z; Bs[lc+3][lr] = b0.w;
    Bs[lc+0][lr+32] = b1.x; Bs[lc+1][lr+32] = b1.y; Bs[lc+2][lr+32] = b1.z; Bs[lc+3][lr+32] = b1.w;
    __syncthreads();
#pragma unroll
    for (int kk = 0; kk < BK; ++kk) {
      const float4 a4 = *(const float4*)&As[kk][ty << 2];
      const float4 b4 = *(const float4*)&Bs[kk][tx << 2];
      const float ar[4] = {a4.x, a4.y, a4.z, a4.w};
      const float br[4] = {b4.x, b4.y, b4.z, b4.w};
#pragma unroll
      for (int i = 0; i < 4; ++i)
#pragma unroll
        for (int j = 0; j < 4; ++j) acc[i][j] += ar[i] * br[j];
    }
    __syncthreads();
  }
#pragma unroll
  for (int i = 0; i < 4; ++i) {
    const int m = m0 + (ty << 2) + i;
    *(float4*)(O0 + (size_t)m * N + n0 + (tx << 2)) =
        make_float4(acc[i][0], acc[i][1], acc[i][2], acc[i][3]);
  }
}

// ================= Flash attention, bf16 MFMA =================
// Q,K,V: [B,H,T,D] bf16. O: [B,T,C] fp32.
// Block: 256 thr (4 waves), Q-tile 64 rows (16/wave), K-tiles of 64.
// mfma_f32_16x16x32_bf16 layouts (verified m89/m91/m120):
//   A-frag: lane holds A[m=l&15][k=quad*8+j]
//   B-frag: lane holds B[k=quad*8+j][n=l&15]
//   C/D:    lane reg r holds D[m=quad*4+r][n=l&15]
#define TQ 64
#define TK 64
#define KROW 72   // LDS row pitch in ushorts (+8 pad kills 16-way frag-read conflicts)

__global__ __launch_bounds__(256) void attn_mfma(
    const unsigned short* __restrict__ Q,
    const unsigned short* __restrict__ K,
    const unsigned short* __restrict__ V,
    float* __restrict__ O)
{
  __shared__ unsigned short Ks[TK * KROW];      // [key][dim]
  __shared__ unsigned short Vt[HD * KROW];      // [dim][key] (transposed)
  __shared__ unsigned short Pw[4][16 * KROW];   // per-wave P round-trip
  const int tid = threadIdx.x;
  const int w = tid >> 6, l = tid & 63;
  const int quad = l >> 4, l15 = l & 15;
  const int qt = blockIdx.x;
  const int bh = blockIdx.y;
  const int q0 = qt * TQ;
  const int qw = q0 + w * 16;           // this wave's first q row
  const size_t hoff = (size_t)bh * T_SEQ * HD;
  const unsigned short* Qh = Q + hoff;
  const unsigned short* Kh = K + hoff;
  const unsigned short* Vh = V + hoff;

  // Q fragments: lane holds Q[qw + l15][quad*8+j + 32*h2], reused across all K-tiles
  short8 qf[2];
  {
    const int qrow = qw + l15;
    qf[0] = *(const short8*)(Qh + (size_t)qrow * HD + quad * 8);
    qf[1] = *(const short8*)(Qh + (size_t)qrow * HD + 32 + quad * 8);
  }

  floatx4 Of[4];
#pragma unroll
  for (int dc = 0; dc < 4; ++dc) Of[dc] = (floatx4){0.f, 0.f, 0.f, 0.f};
  float mprev[4] = {-1e30f, -1e30f, -1e30f, -1e30f};
  float lrun[4] = {0.f, 0.f, 0.f, 0.f};

  const int nkt = qt + 1;
  for (int kt = 0; kt < nkt; ++kt) {
    const int kt0 = kt * TK;
    __syncthreads();   // previous iteration's LDS reads done
    // --- stage K tile [64 key][64 dim] and V^T tile [64 dim][64 key] ---
#pragma unroll
    for (int i = 0; i < 2; ++i) {
      const int idx = i * 256 + tid;
      const int row = idx >> 3, ch = idx & 7;
      *(uint4*)&Ks[row * KROW + ch * 8] =
          *(const uint4*)(Kh + (size_t)(kt0 + row) * HD + ch * 8);
      union { uint4 v; unsigned short s[8]; } u;
      u.v = *(const uint4*)(Vh + (size_t)(kt0 + row) * HD + ch * 8);
#pragma unroll
      for (int e = 0; e < 8; ++e) Vt[(ch * 8 + e) * KROW + row] = u.s[e];
    }
    __syncthreads();

    if (qw + 15 >= kt0) {   // wave-uniform: skip fully-masked tiles
      // --- S = Q K^T ---
      floatx4 Sf[4];
#pragma unroll
      for (int cb = 0; cb < 4; ++cb) {
        Sf[cb] = (floatx4){0.f, 0.f, 0.f, 0.f};
#pragma unroll
        for (int h2 = 0; h2 < 2; ++h2) {
          const short8 kf = *(const short8*)&Ks[(cb * 16 + l15) * KROW + h2 * 32 + quad * 8];
          Sf[cb] = __builtin_amdgcn_mfma_f32_16x16x32_bf16(qf[h2], kf, Sf[cb], 0, 0, 0);
        }
      }
      // --- scale + causal mask ---
      float sv[4][4];
      float rmax[4] = {-1e30f, -1e30f, -1e30f, -1e30f};
#pragma unroll
      for (int cb = 0; cb < 4; ++cb)
#pragma unroll
        for (int r = 0; r < 4; ++r) {
          float s = Sf[cb][r] * 0.125f;
          const int key = kt0 + cb * 16 + l15;
          const int qrow = qw + quad * 4 + r;
          if (key > qrow) s = -1e30f;
          sv[cb][r] = s;
          rmax[r] = fmaxf(rmax[r], s);
        }
      // row-max across the 16 lanes holding this row
#pragma unroll
      for (int r = 0; r < 4; ++r)
#pragma unroll
        for (int m = 1; m < 16; m <<= 1)
          rmax[r] = fmaxf(rmax[r], __shfl_xor(rmax[r], m));
      // online softmax update + write P (bf16) to per-wave LDS
      float alpha[4], psum[4];
#pragma unroll
      for (int r = 0; r < 4; ++r) {
        const float mnew = fmaxf(mprev[r], rmax[r]);
        alpha[r] = __expf(mprev[r] - mnew);
        mprev[r] = mnew;
        float ps = 0.f;
#pragma unroll
        for (int cb = 0; cb < 4; ++cb) {
          const float p = __expf(sv[cb][r] - mnew);
          ps += p;
          Pw[w][(quad * 4 + r) * KROW + cb * 16 + l15] = f2bf(p);
        }
        psum[r] = ps;
      }
#pragma unroll
      for (int r = 0; r < 4; ++r)
#pragma unroll
        for (int m = 1; m < 16; m <<= 1)
          psum[r] += __shfl_xor(psum[r], m);
#pragma unroll
      for (int r = 0; r < 4; ++r) lrun[r] = lrun[r] * alpha[r] + psum[r];
#pragma unroll
      for (int dc = 0; dc < 4; ++dc)
#pragma unroll
        for (int r = 0; r < 4; ++r) Of[dc][r] *= alpha[r];
      // --- O += P V ---
#pragma unroll
      for (int kg = 0; kg < 2; ++kg) {
        const short8 pf = *(const short8*)&Pw[w][l15 * KROW + kg * 32 + quad * 8];
#pragma unroll
        for (int dc = 0; dc < 4; ++dc) {
          const short8 vf = *(const short8*)&Vt[(dc * 16 + l15) * KROW + kg * 32 + quad * 8];
          Of[dc] = __builtin_amdgcn_mfma_f32_16x16x32_bf16(pf, vf, Of[dc], 0, 0, 0);
        }
      }
    }
  }

  // --- epilogue: O[b, q, h*64+dim] = Of / l ---
  const int b = bh >> 4, h = bh & 15;
#pragma unroll
  for (int r = 0; r < 4; ++r) {
    const float inv = 1.f / lrun[r];
    const int q = qw + quad * 4 + r;
#pragma unroll
    for (int dc = 0; dc < 4; ++dc)
      O[(size_t)(b * T_SEQ + q) * CDIM + h * HD + dc * 16 + l15] = Of[dc][r] * inv;
  }
}

extern "C" void kernel_launch(void* const* d_in, const int* in_sizes, int n_in,
                              void* d_out, int out_size, void* d_ws, size_t ws_size,
                              hipStream_t stream) {
  const float* x     = (const float*)d_in[0];  // [B,T,C]
  const float* Wqkv  = (const float*)d_in[1];  // [3C,C]
  const float* Wproj = (const float*)d_in[2];  // [C,C]
  float* out = (float*)d_out;                  // [B,T,C]

  const size_t HSZ = (size_t)NB * NH * T_SEQ * HD;  // 8388608 elems
  unsigned short* qbuf = (unsigned short*)d_ws;     // bf16 [B,H,T,D]
  unsigned short* kbuf = qbuf + HSZ;
  unsigned short* vbuf = kbuf + HSZ;
  float* abuf = (float*)(vbuf + HSZ);               // fp32 [B,T,C]

  // 1) QKV projection (fp32 compute), scatter bf16 to [B,H,T,D]
  dim3 g1(3 * CDIM / BN, MROWS / BM);   // (48,128)
  gemm_qkv<<<g1, 256, 0, stream>>>(x, Wqkv, qbuf, kbuf, vbuf, 3 * CDIM, CDIM);

  // 2) flash attention (bf16 MFMA)
  dim3 g2(T_SEQ / TQ, NB * NH);         // (32,64)
  attn_mfma<<<g2, 256, 0, stream>>>(qbuf, kbuf, vbuf, abuf);

  // 3) output projection (fp32 compute)
  dim3 g3(CDIM / BN, MROWS / BM);       // (16,128)
  gemm_proj<<<g3, 256, 0, stream>>>(abuf, Wproj, out, CDIM, CDIM);
}

// Round 4
// 501.434 us; speedup vs baseline: 13.9640x; 2.5429x over previous
//
#include <hip/hip_runtime.h>

#define T_SEQ 2048
#define NB 4
#define NH 16
#define HD 64
#define CDIM 1024
#define MROWS (NB * T_SEQ)  // 8192

typedef __attribute__((ext_vector_type(8))) short short8;
typedef __attribute__((ext_vector_type(4))) float floatx4;

static __device__ __forceinline__ unsigned short f2bf(float f) {
  union { float f; unsigned int i; } c; c.f = f;
  return (unsigned short)((c.i + 0x7FFFu + ((c.i >> 16) & 1u)) >> 16);
}

// async 16B/lane global->LDS (emits global_load_lds_dwordx4).
// LDS dest is wave-uniform base + lane*16 — layout must be lane-order contiguous.
static __device__ __forceinline__ void gl2lds16(const void* g, void* l) {
  __builtin_amdgcn_global_load_lds(
      (const __attribute__((address_space(1))) unsigned int*)g,
      (__attribute__((address_space(3))) unsigned int*)l, 16, 0, 0);
}

// ---------------- fp32 -> bf16 cast ----------------
__global__ __launch_bounds__(256) void cast_bf16(const float* __restrict__ in,
                                                 unsigned short* __restrict__ out,
                                                 const int n4) {
  const int i = blockIdx.x * 256 + threadIdx.x;
  if (i < n4) {
    const float4 v = ((const float4*)in)[i];
    ushort4 o;
    o.x = f2bf(v.x); o.y = f2bf(v.y); o.z = f2bf(v.z); o.w = f2bf(v.w);
    ((ushort4*)out)[i] = o;
  }
}

// ================= bf16 MFMA GEMM (m97 recipe): C[m,n] = sum_k A[m,k]*B[n,k] ======
// 128x128 tile, 256 thr = 4 waves, each wave 64x64 (4x4 of 16x16x32 MFMA), BK=32.
// mfma_f32_16x16x32_bf16 layouts (verified m89/m91):
//   A-frag: lane holds A[m=l15][k=quad*8+j]; B-frag: lane holds B^T row n=l15, k=quad*8+j
//   C/D: lane reg r holds D[m=quad*4+r][n=l15]

// ---- QKV variant: scatter bf16 into q/k/v [B,H,T,D] ----
__global__ __launch_bounds__(256) void gemm_bf16_qkv(
    const unsigned short* __restrict__ A,   // [M,K] bf16 (x)
    const unsigned short* __restrict__ B,   // [N,K] bf16 (Wqkv)
    unsigned short* __restrict__ Oq,
    unsigned short* __restrict__ Ok,
    unsigned short* __restrict__ Ov,
    const int K)
{
  __shared__ unsigned short As[128 * 32];
  __shared__ unsigned short Bs[128 * 32];
  const int tid = threadIdx.x;
  const int w = tid >> 6, l = tid & 63;
  const int quad = l >> 4, l15 = l & 15;
  const int m0 = blockIdx.y * 128, n0 = blockIdx.x * 128;
  const int wm = (w >> 1) * 64, wn = (w & 1) * 64;
  const int srow = l >> 2, scol = (l & 3) * 8;

  floatx4 acc[4][4];
#pragma unroll
  for (int mi = 0; mi < 4; ++mi)
#pragma unroll
    for (int ni = 0; ni < 4; ++ni) acc[mi][ni] = (floatx4){0.f, 0.f, 0.f, 0.f};

  const unsigned short* Ag = A + (size_t)(m0 + w * 32 + srow) * K + scol;
  const unsigned short* Bg = B + (size_t)(n0 + w * 32 + srow) * K + scol;
  unsigned short* Al0 = &As[(w * 32) * 32];
  unsigned short* Al1 = &As[(w * 32 + 16) * 32];
  unsigned short* Bl0 = &Bs[(w * 32) * 32];
  unsigned short* Bl1 = &Bs[(w * 32 + 16) * 32];

  for (int k0 = 0; k0 < K; k0 += 32) {
    __syncthreads();
    gl2lds16(Ag + k0, Al0);
    gl2lds16(Ag + (size_t)16 * K + k0, Al1);
    gl2lds16(Bg + k0, Bl0);
    gl2lds16(Bg + (size_t)16 * K + k0, Bl1);
    __syncthreads();
    short8 af[4], bfr[4];
#pragma unroll
    for (int mi = 0; mi < 4; ++mi)
      af[mi] = *(const short8*)&As[(wm + mi * 16 + l15) * 32 + quad * 8];
#pragma unroll
    for (int ni = 0; ni < 4; ++ni)
      bfr[ni] = *(const short8*)&Bs[(wn + ni * 16 + l15) * 32 + quad * 8];
#pragma unroll
    for (int mi = 0; mi < 4; ++mi)
#pragma unroll
      for (int ni = 0; ni < 4; ++ni)
        acc[mi][ni] = __builtin_amdgcn_mfma_f32_16x16x32_bf16(af[mi], bfr[ni], acc[mi][ni], 0, 0, 0);
  }

  const int mbase = m0 + wm + quad * 4;
#pragma unroll
  for (int ni = 0; ni < 4; ++ni) {
    const int n = n0 + wn + ni * 16 + l15;
    const int which = n >> 10;
    unsigned short* dst = (which == 0) ? Oq : (which == 1) ? Ok : Ov;
    const int h = (n >> 6) & (NH - 1), d = n & (HD - 1);
#pragma unroll
    for (int mi = 0; mi < 4; ++mi)
#pragma unroll
      for (int r = 0; r < 4; ++r) {
        const int m = mbase + mi * 16 + r;
        const int b = m >> 11, t = m & (T_SEQ - 1);
        dst[(((size_t)(b * NH + h) * T_SEQ + t) << 6) + d] = f2bf(acc[mi][ni][r]);
      }
  }
}

// ---- Proj variant: fp32 [M,N] output ----
__global__ __launch_bounds__(256) void gemm_bf16_proj(
    const unsigned short* __restrict__ A,   // [M,K] bf16 (attn out)
    const unsigned short* __restrict__ B,   // [N,K] bf16 (Wproj)
    float* __restrict__ O,
    const int N, const int K)
{
  __shared__ unsigned short As[128 * 32];
  __shared__ unsigned short Bs[128 * 32];
  const int tid = threadIdx.x;
  const int w = tid >> 6, l = tid & 63;
  const int quad = l >> 4, l15 = l & 15;
  const int m0 = blockIdx.y * 128, n0 = blockIdx.x * 128;
  const int wm = (w >> 1) * 64, wn = (w & 1) * 64;
  const int srow = l >> 2, scol = (l & 3) * 8;

  floatx4 acc[4][4];
#pragma unroll
  for (int mi = 0; mi < 4; ++mi)
#pragma unroll
    for (int ni = 0; ni < 4; ++ni) acc[mi][ni] = (floatx4){0.f, 0.f, 0.f, 0.f};

  const unsigned short* Ag = A + (size_t)(m0 + w * 32 + srow) * K + scol;
  const unsigned short* Bg = B + (size_t)(n0 + w * 32 + srow) * K + scol;
  unsigned short* Al0 = &As[(w * 32) * 32];
  unsigned short* Al1 = &As[(w * 32 + 16) * 32];
  unsigned short* Bl0 = &Bs[(w * 32) * 32];
  unsigned short* Bl1 = &Bs[(w * 32 + 16) * 32];

  for (int k0 = 0; k0 < K; k0 += 32) {
    __syncthreads();
    gl2lds16(Ag + k0, Al0);
    gl2lds16(Ag + (size_t)16 * K + k0, Al1);
    gl2lds16(Bg + k0, Bl0);
    gl2lds16(Bg + (size_t)16 * K + k0, Bl1);
    __syncthreads();
    short8 af[4], bfr[4];
#pragma unroll
    for (int mi = 0; mi < 4; ++mi)
      af[mi] = *(const short8*)&As[(wm + mi * 16 + l15) * 32 + quad * 8];
#pragma unroll
    for (int ni = 0; ni < 4; ++ni)
      bfr[ni] = *(const short8*)&Bs[(wn + ni * 16 + l15) * 32 + quad * 8];
#pragma unroll
    for (int mi = 0; mi < 4; ++mi)
#pragma unroll
      for (int ni = 0; ni < 4; ++ni)
        acc[mi][ni] = __builtin_amdgcn_mfma_f32_16x16x32_bf16(af[mi], bfr[ni], acc[mi][ni], 0, 0, 0);
  }

#pragma unroll
  for (int mi = 0; mi < 4; ++mi)
#pragma unroll
    for (int r = 0; r < 4; ++r) {
      const int m = m0 + wm + mi * 16 + quad * 4 + r;
#pragma unroll
      for (int ni = 0; ni < 4; ++ni)
        O[(size_t)m * N + n0 + wn + ni * 16 + l15] = acc[mi][ni][r];
    }
}

// ================= Flash attention, bf16 MFMA =================
// Q,K,V: [B,H,T,D] bf16. O: [B,T,C] bf16.
#define TQ 64
#define TK 64
#define KROW 72   // LDS row pitch (+8 pad)

__global__ __launch_bounds__(256) void attn_mfma(
    const unsigned short* __restrict__ Q,
    const unsigned short* __restrict__ K,
    const unsigned short* __restrict__ V,
    unsigned short* __restrict__ O)
{
  __shared__ unsigned short Ks[TK * KROW];      // [key][dim]
  __shared__ unsigned short Vt[HD * KROW];      // [dim][key]
  __shared__ unsigned short Pw[4][16 * KROW];   // per-wave P round-trip
  const int tid = threadIdx.x;
  const int w = tid >> 6, l = tid & 63;
  const int quad = l >> 4, l15 = l & 15;
  const int qt = blockIdx.x;
  const int bh = blockIdx.y;
  const int qw = qt * TQ + w * 16;
  const size_t hoff = (size_t)bh * T_SEQ * HD;
  const unsigned short* Qh = Q + hoff;
  const unsigned short* Kh = K + hoff;
  const unsigned short* Vh = V + hoff;

  short8 qf[2];
  {
    const int qrow = qw + l15;
    qf[0] = *(const short8*)(Qh + (size_t)qrow * HD + quad * 8);
    qf[1] = *(const short8*)(Qh + (size_t)qrow * HD + 32 + quad * 8);
  }

  floatx4 Of[4];
#pragma unroll
  for (int dc = 0; dc < 4; ++dc) Of[dc] = (floatx4){0.f, 0.f, 0.f, 0.f};
  float mprev[4] = {-1e30f, -1e30f, -1e30f, -1e30f};
  float lrun[4] = {0.f, 0.f, 0.f, 0.f};

  const int nkt = qt + 1;
  for (int kt = 0; kt < nkt; ++kt) {
    const int kt0 = kt * TK;
    __syncthreads();
#pragma unroll
    for (int i = 0; i < 2; ++i) {
      const int idx = i * 256 + tid;
      const int row = idx >> 3, ch = idx & 7;
      *(uint4*)&Ks[row * KROW + ch * 8] =
          *(const uint4*)(Kh + (size_t)(kt0 + row) * HD + ch * 8);
      union { uint4 v; unsigned short s[8]; } u;
      u.v = *(const uint4*)(Vh + (size_t)(kt0 + row) * HD + ch * 8);
#pragma unroll
      for (int e = 0; e < 8; ++e) Vt[(ch * 8 + e) * KROW + row] = u.s[e];
    }
    __syncthreads();

    if (qw + 15 >= kt0) {
      floatx4 Sf[4];
#pragma unroll
      for (int cb = 0; cb < 4; ++cb) {
        Sf[cb] = (floatx4){0.f, 0.f, 0.f, 0.f};
#pragma unroll
        for (int h2 = 0; h2 < 2; ++h2) {
          const short8 kf = *(const short8*)&Ks[(cb * 16 + l15) * KROW + h2 * 32 + quad * 8];
          Sf[cb] = __builtin_amdgcn_mfma_f32_16x16x32_bf16(qf[h2], kf, Sf[cb], 0, 0, 0);
        }
      }
      float sv[4][4];
      float rmax[4] = {-1e30f, -1e30f, -1e30f, -1e30f};
#pragma unroll
      for (int cb = 0; cb < 4; ++cb)
#pragma unroll
        for (int r = 0; r < 4; ++r) {
          float s = Sf[cb][r] * 0.125f;
          const int key = kt0 + cb * 16 + l15;
          const int qrow = qw + quad * 4 + r;
          if (key > qrow) s = -1e30f;
          sv[cb][r] = s;
          rmax[r] = fmaxf(rmax[r], s);
        }
#pragma unroll
      for (int r = 0; r < 4; ++r)
#pragma unroll
        for (int m = 1; m < 16; m <<= 1)
          rmax[r] = fmaxf(rmax[r], __shfl_xor(rmax[r], m));
      float alpha[4], psum[4];
#pragma unroll
      for (int r = 0; r < 4; ++r) {
        const float mnew = fmaxf(mprev[r], rmax[r]);
        alpha[r] = __expf(mprev[r] - mnew);
        mprev[r] = mnew;
        float ps = 0.f;
#pragma unroll
        for (int cb = 0; cb < 4; ++cb) {
          const float p = __expf(sv[cb][r] - mnew);
          ps += p;
          Pw[w][(quad * 4 + r) * KROW + cb * 16 + l15] = f2bf(p);
        }
        psum[r] = ps;
      }
#pragma unroll
      for (int r = 0; r < 4; ++r)
#pragma unroll
        for (int m = 1; m < 16; m <<= 1)
          psum[r] += __shfl_xor(psum[r], m);
#pragma unroll
      for (int r = 0; r < 4; ++r) lrun[r] = lrun[r] * alpha[r] + psum[r];
#pragma unroll
      for (int dc = 0; dc < 4; ++dc)
#pragma unroll
        for (int r = 0; r < 4; ++r) Of[dc][r] *= alpha[r];
#pragma unroll
      for (int kg = 0; kg < 2; ++kg) {
        const short8 pf = *(const short8*)&Pw[w][l15 * KROW + kg * 32 + quad * 8];
#pragma unroll
        for (int dc = 0; dc < 4; ++dc) {
          const short8 vf = *(const short8*)&Vt[(dc * 16 + l15) * KROW + kg * 32 + quad * 8];
          Of[dc] = __builtin_amdgcn_mfma_f32_16x16x32_bf16(pf, vf, Of[dc], 0, 0, 0);
        }
      }
    }
  }

  const int b = bh >> 4, h = bh & 15;
#pragma unroll
  for (int r = 0; r < 4; ++r) {
    const float inv = 1.f / lrun[r];
    const int q = qw + quad * 4 + r;
#pragma unroll
    for (int dc = 0; dc < 4; ++dc)
      O[(size_t)(b * T_SEQ + q) * CDIM + h * HD + dc * 16 + l15] = f2bf(Of[dc][r] * inv);
  }
}

extern "C" void kernel_launch(void* const* d_in, const int* in_sizes, int n_in,
                              void* d_out, int out_size, void* d_ws, size_t ws_size,
                              hipStream_t stream) {
  const float* x     = (const float*)d_in[0];  // [B,T,C]
  const float* Wqkv  = (const float*)d_in[1];  // [3C,C]
  const float* Wproj = (const float*)d_in[2];  // [C,C]
  float* out = (float*)d_out;                  // [B,T,C] fp32

  const size_t XSZ = (size_t)MROWS * CDIM;          // 8388608
  const size_t WQSZ = (size_t)3 * CDIM * CDIM;      // 3145728
  const size_t WPSZ = (size_t)CDIM * CDIM;          // 1048576
  unsigned short* xb  = (unsigned short*)d_ws;      // bf16 x
  unsigned short* wqb = xb + XSZ;                   // bf16 Wqkv
  unsigned short* wpb = wqb + WQSZ;                 // bf16 Wproj
  unsigned short* qbuf = wpb + WPSZ;                // bf16 [B,H,T,D]
  unsigned short* kbuf = qbuf + XSZ;
  unsigned short* vbuf = kbuf + XSZ;
  unsigned short* abuf = vbuf + XSZ;                // bf16 [B,T,C]

  // 0) casts to bf16
  cast_bf16<<<XSZ / 4 / 256, 256, 0, stream>>>(x, xb, (int)(XSZ / 4));
  cast_bf16<<<WQSZ / 4 / 256, 256, 0, stream>>>(Wqkv, wqb, (int)(WQSZ / 4));
  cast_bf16<<<WPSZ / 4 / 256, 256, 0, stream>>>(Wproj, wpb, (int)(WPSZ / 4));

  // 1) QKV projection (bf16 MFMA), scatter to [B,H,T,D]
  dim3 g1(3 * CDIM / 128, MROWS / 128);   // (24,64)
  gemm_bf16_qkv<<<g1, 256, 0, stream>>>(xb, wqb, qbuf, kbuf, vbuf, CDIM);

  // 2) flash attention (bf16 MFMA)
  dim3 g2(T_SEQ / TQ, NB * NH);           // (32,64)
  attn_mfma<<<g2, 256, 0, stream>>>(qbuf, kbuf, vbuf, abuf);

  // 3) output projection (bf16 MFMA, fp32 out)
  dim3 g3(CDIM / 128, MROWS / 128);       // (8,64)
  gemm_bf16_proj<<<g3, 256, 0, stream>>>(abuf, wpb, out, CDIM, CDIM);
}

// Round 5
// 339.650 us; speedup vs baseline: 20.6154x; 1.4763x over previous
//
#include <hip/hip_runtime.h>

#define T_SEQ 2048
#define NB 4
#define NH 16
#define HD 64
#define CDIM 1024
#define MROWS (NB * T_SEQ)  // 8192

typedef __attribute__((ext_vector_type(8))) short short8;
typedef __attribute__((ext_vector_type(4))) float floatx4;

static __device__ __forceinline__ unsigned short f2bf(float f) {
  union { float f; unsigned int i; } c; c.f = f;
  return (unsigned short)((c.i + 0x7FFFu + ((c.i >> 16) & 1u)) >> 16);
}

// async 16B/lane global->LDS (emits global_load_lds_dwordx4).
static __device__ __forceinline__ void gl2lds16(const void* g, void* l) {
  __builtin_amdgcn_global_load_lds(
      (const __attribute__((address_space(1))) unsigned int*)g,
      (__attribute__((address_space(3))) unsigned int*)l, 16, 0, 0);
}

// ---------------- fp32 -> bf16 cast ----------------
__global__ __launch_bounds__(256) void cast_bf16(const float* __restrict__ in,
                                                 unsigned short* __restrict__ out,
                                                 const int n4) {
  const int i = blockIdx.x * 256 + threadIdx.x;
  if (i < n4) {
    const float4 v = ((const float4*)in)[i];
    ushort4 o;
    o.x = f2bf(v.x); o.y = f2bf(v.y); o.z = f2bf(v.z); o.w = f2bf(v.w);
    ((ushort4*)out)[i] = o;
  }
}

__global__ void zero1(int* p) { *p = 0; }

// ================= bf16 MFMA GEMM (m97 recipe): C[m,n] = sum_k A[m,k]*B[n,k] ======
// 128x128 tile, 256 thr = 4 waves, each wave 64x64 (4x4 of 16x16x32 MFMA), BK=32.
//   A-frag: lane holds A[m=l15][k=quad*8+j]; B-frag: lane holds B row n=l15, k=quad*8+j
//   C/D: lane reg r holds D[m=quad*4+r][n=l15]

// ---- QKV variant: Q,K scattered [B,H,T,D]; V scattered TRANSPOSED [B,H,D,T] ----
__global__ __launch_bounds__(256) void gemm_bf16_qkv(
    const unsigned short* __restrict__ A,   // [M,K] bf16 (x)
    const unsigned short* __restrict__ B,   // [N,K] bf16 (Wqkv)
    unsigned short* __restrict__ Oq,
    unsigned short* __restrict__ Ok,
    unsigned short* __restrict__ Ovt,       // [B,H,D,T]
    const int K)
{
  __shared__ unsigned short As[128 * 32];
  __shared__ unsigned short Bs[128 * 32];
  const int tid = threadIdx.x;
  const int w = tid >> 6, l = tid & 63;
  const int quad = l >> 4, l15 = l & 15;
  const int m0 = blockIdx.y * 128, n0 = blockIdx.x * 128;
  const int wm = (w >> 1) * 64, wn = (w & 1) * 64;
  const int srow = l >> 2, scol = (l & 3) * 8;

  floatx4 acc[4][4];
#pragma unroll
  for (int mi = 0; mi < 4; ++mi)
#pragma unroll
    for (int ni = 0; ni < 4; ++ni) acc[mi][ni] = (floatx4){0.f, 0.f, 0.f, 0.f};

  const unsigned short* Ag = A + (size_t)(m0 + w * 32 + srow) * K + scol;
  const unsigned short* Bg = B + (size_t)(n0 + w * 32 + srow) * K + scol;
  unsigned short* Al0 = &As[(w * 32) * 32];
  unsigned short* Al1 = &As[(w * 32 + 16) * 32];
  unsigned short* Bl0 = &Bs[(w * 32) * 32];
  unsigned short* Bl1 = &Bs[(w * 32 + 16) * 32];

  for (int k0 = 0; k0 < K; k0 += 32) {
    __syncthreads();
    gl2lds16(Ag + k0, Al0);
    gl2lds16(Ag + (size_t)16 * K + k0, Al1);
    gl2lds16(Bg + k0, Bl0);
    gl2lds16(Bg + (size_t)16 * K + k0, Bl1);
    __syncthreads();
    short8 af[4], bfr[4];
#pragma unroll
    for (int mi = 0; mi < 4; ++mi)
      af[mi] = *(const short8*)&As[(wm + mi * 16 + l15) * 32 + quad * 8];
#pragma unroll
    for (int ni = 0; ni < 4; ++ni)
      bfr[ni] = *(const short8*)&Bs[(wn + ni * 16 + l15) * 32 + quad * 8];
#pragma unroll
    for (int mi = 0; mi < 4; ++mi)
#pragma unroll
      for (int ni = 0; ni < 4; ++ni)
        acc[mi][ni] = __builtin_amdgcn_mfma_f32_16x16x32_bf16(af[mi], bfr[ni], acc[mi][ni], 0, 0, 0);
  }

  const int mbase = m0 + wm + quad * 4;
#pragma unroll
  for (int ni = 0; ni < 4; ++ni) {
    const int n = n0 + wn + ni * 16 + l15;
    const int which = n >> 10;
    const int h = (n >> 6) & (NH - 1), d = n & (HD - 1);
    if (which == 2) {
      // V transposed: [B,H,D,T]; r=0..3 are 4 consecutive t -> ushort4 store
#pragma unroll
      for (int mi = 0; mi < 4; ++mi) {
        const int m = mbase + mi * 16;
        const int b = m >> 11, t0 = m & (T_SEQ - 1);
        ushort4 pk;
        pk.x = f2bf(acc[mi][ni][0]); pk.y = f2bf(acc[mi][ni][1]);
        pk.z = f2bf(acc[mi][ni][2]); pk.w = f2bf(acc[mi][ni][3]);
        *(ushort4*)(Ovt + ((size_t)((b * NH + h) * HD + d) << 11) + t0) = pk;
      }
    } else {
      unsigned short* dst = (which == 0) ? Oq : Ok;
#pragma unroll
      for (int mi = 0; mi < 4; ++mi)
#pragma unroll
        for (int r = 0; r < 4; ++r) {
          const int m = mbase + mi * 16 + r;
          const int b = m >> 11, t = m & (T_SEQ - 1);
          dst[(((size_t)(b * NH + h) * T_SEQ + t) << 6) + d] = f2bf(acc[mi][ni][r]);
        }
    }
  }
}

// ---- Proj variant: fp32 [M,N] output ----
__global__ __launch_bounds__(256) void gemm_bf16_proj(
    const unsigned short* __restrict__ A,   // [M,K] bf16 (attn out)
    const unsigned short* __restrict__ B,   // [N,K] bf16 (Wproj)
    float* __restrict__ O,
    const int N, const int K)
{
  __shared__ unsigned short As[128 * 32];
  __shared__ unsigned short Bs[128 * 32];
  const int tid = threadIdx.x;
  const int w = tid >> 6, l = tid & 63;
  const int quad = l >> 4, l15 = l & 15;
  const int m0 = blockIdx.y * 128, n0 = blockIdx.x * 128;
  const int wm = (w >> 1) * 64, wn = (w & 1) * 64;
  const int srow = l >> 2, scol = (l & 3) * 8;

  floatx4 acc[4][4];
#pragma unroll
  for (int mi = 0; mi < 4; ++mi)
#pragma unroll
    for (int ni = 0; ni < 4; ++ni) acc[mi][ni] = (floatx4){0.f, 0.f, 0.f, 0.f};

  const unsigned short* Ag = A + (size_t)(m0 + w * 32 + srow) * K + scol;
  const unsigned short* Bg = B + (size_t)(n0 + w * 32 + srow) * K + scol;
  unsigned short* Al0 = &As[(w * 32) * 32];
  unsigned short* Al1 = &As[(w * 32 + 16) * 32];
  unsigned short* Bl0 = &Bs[(w * 32) * 32];
  unsigned short* Bl1 = &Bs[(w * 32 + 16) * 32];

  for (int k0 = 0; k0 < K; k0 += 32) {
    __syncthreads();
    gl2lds16(Ag + k0, Al0);
    gl2lds16(Ag + (size_t)16 * K + k0, Al1);
    gl2lds16(Bg + k0, Bl0);
    gl2lds16(Bg + (size_t)16 * K + k0, Bl1);
    __syncthreads();
    short8 af[4], bfr[4];
#pragma unroll
    for (int mi = 0; mi < 4; ++mi)
      af[mi] = *(const short8*)&As[(wm + mi * 16 + l15) * 32 + quad * 8];
#pragma unroll
    for (int ni = 0; ni < 4; ++ni)
      bfr[ni] = *(const short8*)&Bs[(wn + ni * 16 + l15) * 32 + quad * 8];
#pragma unroll
    for (int mi = 0; mi < 4; ++mi)
#pragma unroll
      for (int ni = 0; ni < 4; ++ni)
        acc[mi][ni] = __builtin_amdgcn_mfma_f32_16x16x32_bf16(af[mi], bfr[ni], acc[mi][ni], 0, 0, 0);
  }

#pragma unroll
  for (int mi = 0; mi < 4; ++mi)
#pragma unroll
    for (int r = 0; r < 4; ++r) {
      const int m = m0 + wm + mi * 16 + quad * 4 + r;
#pragma unroll
      for (int ni = 0; ni < 4; ++ni)
        O[(size_t)m * N + n0 + wn + ni * 16 + l15] = acc[mi][ni][r];
    }
}

// ================= Flash attention, bf16 MFMA, work-queue =================
// Q,K: [B,H,T,D] bf16. Vt: [B,H,D,T] bf16. O: [B,T,C] bf16.
// Items ordered heavy-first (qt descending); blocks pull via atomicAdd.
#define TQ 64
#define TK 64
#define KROW 72      // LDS row pitch (+8 pad)
#define NITEMS ((T_SEQ / TQ) * NB * NH)   // 2048

__global__ __launch_bounds__(256) void attn_mfma(
    const unsigned short* __restrict__ Q,
    const unsigned short* __restrict__ K,
    const unsigned short* __restrict__ Vt,
    unsigned short* __restrict__ O,
    int* __restrict__ cnt)
{
  __shared__ unsigned short Ks[TK * KROW];      // [key][dim]
  __shared__ unsigned short Vts[HD * KROW];     // [dim][key]
  __shared__ unsigned short Pw[4][16 * KROW];   // per-wave P round-trip
  __shared__ int s_item;
  const int tid = threadIdx.x;
  const int w = tid >> 6, l = tid & 63;
  const int quad = l >> 4, l15 = l & 15;
  // staging indices (per thread, 2 chunks of 16B each for K and Vt)
  const int srow0 = tid >> 3, sch = (tid & 7) * 8;   // rows 0..31
  for (;;) {
    if (tid == 0) s_item = atomicAdd(cnt, 1);
    __syncthreads();
    const int item = s_item;
    if (item >= NITEMS) return;
    const int qt = (T_SEQ / TQ) - 1 - (item >> 6);   // heavy first
    const int bh = item & 63;
    const int qw = qt * TQ + w * 16;
    const size_t hoff = (size_t)bh * T_SEQ * HD;
    const unsigned short* Qh = Q + hoff;
    const unsigned short* Kh = K + hoff;
    const unsigned short* Vth = Vt + hoff;   // [D][T] rows

    short8 qf[2];
    {
      const int qrow = qw + l15;
      qf[0] = *(const short8*)(Qh + (size_t)qrow * HD + quad * 8);
      qf[1] = *(const short8*)(Qh + (size_t)qrow * HD + 32 + quad * 8);
    }

    floatx4 Of[4];
#pragma unroll
    for (int dc = 0; dc < 4; ++dc) Of[dc] = (floatx4){0.f, 0.f, 0.f, 0.f};
    float mprev[4] = {-1e30f, -1e30f, -1e30f, -1e30f};
    float lrun[4] = {0.f, 0.f, 0.f, 0.f};

    const int nkt = qt + 1;
    for (int kt = 0; kt < nkt; ++kt) {
      const int kt0 = kt * TK;
      __syncthreads();
      // stage K [64 key][64 dim] and Vt [64 dim][64 key], vector writes
#pragma unroll
      for (int i = 0; i < 2; ++i) {
        const int row = srow0 + i * 32;
        *(uint4*)&Ks[row * KROW + sch] =
            *(const uint4*)(Kh + (size_t)(kt0 + row) * HD + sch);
        *(uint4*)&Vts[row * KROW + sch] =
            *(const uint4*)(Vth + ((size_t)row << 11) + kt0 + sch);
      }
      __syncthreads();

      if (qw + 15 >= kt0) {
        floatx4 Sf[4];
#pragma unroll
        for (int cb = 0; cb < 4; ++cb) {
          Sf[cb] = (floatx4){0.f, 0.f, 0.f, 0.f};
#pragma unroll
          for (int h2 = 0; h2 < 2; ++h2) {
            const short8 kf = *(const short8*)&Ks[(cb * 16 + l15) * KROW + h2 * 32 + quad * 8];
            Sf[cb] = __builtin_amdgcn_mfma_f32_16x16x32_bf16(qf[h2], kf, Sf[cb], 0, 0, 0);
          }
        }
        float sv[4][4];
        float rmax[4] = {-1e30f, -1e30f, -1e30f, -1e30f};
#pragma unroll
        for (int cb = 0; cb < 4; ++cb)
#pragma unroll
          for (int r = 0; r < 4; ++r) {
            float s = Sf[cb][r] * 0.125f;
            const int key = kt0 + cb * 16 + l15;
            const int qrow = qw + quad * 4 + r;
            if (key > qrow) s = -1e30f;
            sv[cb][r] = s;
            rmax[r] = fmaxf(rmax[r], s);
          }
#pragma unroll
        for (int r = 0; r < 4; ++r)
#pragma unroll
          for (int m = 1; m < 16; m <<= 1)
            rmax[r] = fmaxf(rmax[r], __shfl_xor(rmax[r], m));
        float alpha[4], psum[4];
#pragma unroll
        for (int r = 0; r < 4; ++r) {
          const float mnew = fmaxf(mprev[r], rmax[r]);
          alpha[r] = __expf(mprev[r] - mnew);
          mprev[r] = mnew;
          float ps = 0.f;
#pragma unroll
          for (int cb = 0; cb < 4; ++cb) {
            const float p = __expf(sv[cb][r] - mnew);
            ps += p;
            Pw[w][(quad * 4 + r) * KROW + cb * 16 + l15] = f2bf(p);
          }
          psum[r] = ps;
        }
#pragma unroll
        for (int r = 0; r < 4; ++r)
#pragma unroll
          for (int m = 1; m < 16; m <<= 1)
            psum[r] += __shfl_xor(psum[r], m);
#pragma unroll
        for (int r = 0; r < 4; ++r) lrun[r] = lrun[r] * alpha[r] + psum[r];
#pragma unroll
        for (int dc = 0; dc < 4; ++dc)
#pragma unroll
          for (int r = 0; r < 4; ++r) Of[dc][r] *= alpha[r];
#pragma unroll
        for (int kg = 0; kg < 2; ++kg) {
          const short8 pf = *(const short8*)&Pw[w][l15 * KROW + kg * 32 + quad * 8];
#pragma unroll
          for (int dc = 0; dc < 4; ++dc) {
            const short8 vf = *(const short8*)&Vts[(dc * 16 + l15) * KROW + kg * 32 + quad * 8];
            Of[dc] = __builtin_amdgcn_mfma_f32_16x16x32_bf16(pf, vf, Of[dc], 0, 0, 0);
          }
        }
      }
    }

    const int b = bh >> 4, h = bh & 15;
#pragma unroll
    for (int r = 0; r < 4; ++r) {
      const float inv = 1.f / lrun[r];
      const int q = qw + quad * 4 + r;
#pragma unroll
      for (int dc = 0; dc < 4; ++dc)
        O[(size_t)(b * T_SEQ + q) * CDIM + h * HD + dc * 16 + l15] = f2bf(Of[dc][r] * inv);
    }
  }
}

extern "C" void kernel_launch(void* const* d_in, const int* in_sizes, int n_in,
                              void* d_out, int out_size, void* d_ws, size_t ws_size,
                              hipStream_t stream) {
  const float* x     = (const float*)d_in[0];  // [B,T,C]
  const float* Wqkv  = (const float*)d_in[1];  // [3C,C]
  const float* Wproj = (const float*)d_in[2];  // [C,C]
  float* out = (float*)d_out;                  // [B,T,C] fp32

  const size_t XSZ = (size_t)MROWS * CDIM;          // 8388608
  const size_t WQSZ = (size_t)3 * CDIM * CDIM;      // 3145728
  const size_t WPSZ = (size_t)CDIM * CDIM;          // 1048576
  unsigned short* xb  = (unsigned short*)d_ws;      // bf16 x
  unsigned short* wqb = xb + XSZ;                   // bf16 Wqkv
  unsigned short* wpb = wqb + WQSZ;                 // bf16 Wproj
  unsigned short* qbuf = wpb + WPSZ;                // bf16 [B,H,T,D]
  unsigned short* kbuf = qbuf + XSZ;
  unsigned short* vtbuf = kbuf + XSZ;               // bf16 [B,H,D,T]
  unsigned short* abuf = vtbuf + XSZ;               // bf16 [B,T,C]
  int* cnt = (int*)(abuf + XSZ);

  // 0) casts to bf16 + zero work-queue counter
  cast_bf16<<<XSZ / 4 / 256, 256, 0, stream>>>(x, xb, (int)(XSZ / 4));
  cast_bf16<<<WQSZ / 4 / 256, 256, 0, stream>>>(Wqkv, wqb, (int)(WQSZ / 4));
  cast_bf16<<<WPSZ / 4 / 256, 256, 0, stream>>>(Wproj, wpb, (int)(WPSZ / 4));
  zero1<<<1, 1, 0, stream>>>(cnt);

  // 1) QKV projection (bf16 MFMA): Q,K -> [B,H,T,D]; V -> [B,H,D,T]
  dim3 g1(3 * CDIM / 128, MROWS / 128);   // (24,64)
  gemm_bf16_qkv<<<g1, 256, 0, stream>>>(xb, wqb, qbuf, kbuf, vtbuf, CDIM);

  // 2) flash attention (bf16 MFMA), work-queue heavy-first
  attn_mfma<<<1280, 256, 0, stream>>>(qbuf, kbuf, vtbuf, abuf, cnt);

  // 3) output projection (bf16 MFMA, fp32 out)
  dim3 g3(CDIM / 128, MROWS / 128);       // (8,64)
  gemm_bf16_proj<<<g3, 256, 0, stream>>>(abuf, wpb, out, CDIM, CDIM);
}